// Round 3
// baseline (226.655 us; speedup 1.0000x reference)
//
#include <hip/hip_runtime.h>
#include <hip/hip_bf16.h>

typedef __attribute__((ext_vector_type(8))) __bf16 bf16x8;
typedef __attribute__((ext_vector_type(4))) float f32x4;

#define BM 128
#define BN 128
#define BKF 64              // f32 k-elements staged per K-step
#define DDIM 256
#define KCENT 1024
#define NSTEP (DDIM / BKF)  // 4

union FragU { uint4 u; bf16x8 f; };

__device__ inline unsigned int pk2(float lo, float hi) {
    union { __hip_bfloat16 h; unsigned short u; } a, b;
    a.h = __float2bfloat16(lo);
    b.h = __float2bfloat16(hi);
    return (unsigned int)a.u | ((unsigned int)b.u << 16);
}

// 128x128 tile, 4 waves (2x2 of 64x64), mfma_f32_16x16x32_bf16, NT-GEMM:
// cross[i][j] = sum_d x[i][d]*centers[j][d]. Both LDS tiles row-major
// [row][64 bf16] = [row][128 B], 16B slots XOR-swizzled by (row&7) so both
// the staging ds_write_b128 and fragment ds_read_b128 stay low-conflict.
__global__ __launch_bounds__(256, 2) void rbf_kernel(
    const float* __restrict__ x,
    const float* __restrict__ centers,
    const float* __restrict__ sigmas,
    float* __restrict__ out, int Brows)
{
    __shared__ __align__(16) unsigned char ldsA[BM * 128];
    __shared__ __align__(16) unsigned char ldsB[BN * 128];
    __shared__ float s_redA[256];
    __shared__ float s_redB[256];
    __shared__ float s_x2[BM];
    __shared__ float s_c2[BN];
    __shared__ float s_scale[BN];

    const int t = threadIdx.x;
    const int mrow0 = blockIdx.y * BM;
    const int ncol0 = blockIdx.x * BN;

    // staging role: row r (0..127), half h (32 f32 = 128 B)
    const int r = t >> 1;
    const int h = t & 1;
    // compute role
    const int lane = t & 63;
    const int wave = t >> 6;
    const int wr = wave >> 1, wc = wave & 1;
    const int q = lane >> 4, r16 = lane & 15;

    f32x4 acc[4][4];
#pragma unroll
    for (int i = 0; i < 4; ++i)
#pragma unroll
        for (int j = 0; j < 4; ++j)
            acc[i][j] = (f32x4){0.f, 0.f, 0.f, 0.f};

    float sa = 0.f, sb = 0.f;  // f32 sum-of-squares for x-row-half / center-row-half

    const float4* __restrict__ xg = (const float4*)(x + (size_t)(mrow0 + r) * DDIM);
    const float4* __restrict__ cg = (const float4*)(centers + (size_t)(ncol0 + r) * DDIM);

    for (int ks = 0; ks < NSTEP; ++ks) {
        // ---- global loads (issued before the barrier; latency overlaps the
        //      tail of other waves' previous compute) ----
        float4 va[8], vb[8];
        const int base = ks * (BKF / 4) + h * 8;  // float4 units
#pragma unroll
        for (int c = 0; c < 8; ++c) { va[c] = xg[base + c]; vb[c] = cg[base + c]; }

        // f32 sum-of-squares (exact inputs, not bf16-rounded)
#pragma unroll
        for (int c = 0; c < 8; ++c) {
            sa += va[c].x * va[c].x + va[c].y * va[c].y + va[c].z * va[c].z + va[c].w * va[c].w;
            sb += vb[c].x * vb[c].x + vb[c].y * vb[c].y + vb[c].z * vb[c].z + vb[c].w * vb[c].w;
        }

        __syncthreads();  // previous iteration's fragment reads complete

        // ---- convert + swizzled LDS write: 4x 16B chunks per operand ----
#pragma unroll
        for (int c = 0; c < 4; ++c) {
            uint4 pa, pb;
            pa.x = pk2(va[2 * c].x, va[2 * c].y);
            pa.y = pk2(va[2 * c].z, va[2 * c].w);
            pa.z = pk2(va[2 * c + 1].x, va[2 * c + 1].y);
            pa.w = pk2(va[2 * c + 1].z, va[2 * c + 1].w);
            pb.x = pk2(vb[2 * c].x, vb[2 * c].y);
            pb.y = pk2(vb[2 * c].z, vb[2 * c].w);
            pb.z = pk2(vb[2 * c + 1].x, vb[2 * c + 1].y);
            pb.w = pk2(vb[2 * c + 1].z, vb[2 * c + 1].w);
            const int slot = ((h * 4 + c) ^ (r & 7)) << 4;
            *(uint4*)(ldsA + r * 128 + slot) = pa;
            *(uint4*)(ldsB + r * 128 + slot) = pb;
        }

        __syncthreads();

        // ---- fragment reads + 32 MFMAs ----
        FragU bfr[4][2];
#pragma unroll
        for (int fn = 0; fn < 4; ++fn) {
            const int row = wc * 64 + fn * 16 + r16;
#pragma unroll
            for (int kk = 0; kk < 2; ++kk) {
                const int slot = ((kk * 4 + q) ^ (row & 7)) << 4;
                bfr[fn][kk].u = *(const uint4*)(ldsB + row * 128 + slot);
            }
        }
#pragma unroll
        for (int fm = 0; fm < 4; ++fm) {
            const int row = wr * 64 + fm * 16 + r16;
            FragU afr[2];
#pragma unroll
            for (int kk = 0; kk < 2; ++kk) {
                const int slot = ((kk * 4 + q) ^ (row & 7)) << 4;
                afr[kk].u = *(const uint4*)(ldsA + row * 128 + slot);
            }
#pragma unroll
            for (int fn = 0; fn < 4; ++fn) {
                acc[fm][fn] = __builtin_amdgcn_mfma_f32_16x16x32_bf16(
                    afr[0].f, bfr[fn][0].f, acc[fm][fn], 0, 0, 0);
                acc[fm][fn] = __builtin_amdgcn_mfma_f32_16x16x32_bf16(
                    afr[1].f, bfr[fn][1].f, acc[fm][fn], 0, 0, 0);
            }
        }
    }

    // ---- reduce half-row sums -> x2[128], c2[128], scale[128] ----
    s_redA[t] = sa;
    s_redB[t] = sb;
    __syncthreads();
    if (t < 128) {
        s_x2[t] = s_redA[2 * t] + s_redA[2 * t + 1];
        s_c2[t] = s_redB[2 * t] + s_redB[2 * t + 1];
        const float sg = sigmas[ncol0 + t];
        s_scale[t] = -0.5f / (sg * sg);
    }
    __syncthreads();

    // ---- epilogue: sqdist = x2 + c2 - 2*cross; out = exp(scale*sqdist) ----
    // C/D layout (m89-verified): col = lane&15, row = (lane>>4)*4 + reg
    float* outp = out + (size_t)mrow0 * KCENT + ncol0;
#pragma unroll
    for (int fm = 0; fm < 4; ++fm) {
#pragma unroll
        for (int fn = 0; fn < 4; ++fn) {
            const int il = wr * 64 + fm * 16 + q * 4;
            const int j = wc * 64 + fn * 16 + r16;
            const float c2v = s_c2[j];
            const float sc = s_scale[j];
#pragma unroll
            for (int rg = 0; rg < 4; ++rg) {
                const float sq = s_x2[il + rg] + c2v - 2.0f * acc[fm][fn][rg];
                outp[(size_t)(il + rg) * KCENT + j] = __expf(sq * sc);
            }
        }
    }
}

extern "C" void kernel_launch(void* const* d_in, const int* in_sizes, int n_in,
                              void* d_out, int out_size, void* d_ws, size_t ws_size,
                              hipStream_t stream) {
    const float* x = (const float*)d_in[0];
    const float* centers = (const float*)d_in[1];
    const float* sigmas = (const float*)d_in[2];
    float* out = (float*)d_out;

    const int Brows = in_sizes[0] / DDIM;          // 32768
    dim3 grid(KCENT / BN, Brows / BM);             // (8, 256) — x fastest: N-blocks
                                                   // sharing an A-panel dispatch
                                                   // adjacently (L2/L3 locality)
    rbf_kernel<<<grid, dim3(256), 0, stream>>>(x, centers, sigmas, out, Brows);
}